// Round 21
// baseline (12142.986 us; speedup 1.0000x reference)
//
#include <hip/hip_runtime.h>

// SpikeMLP: bit-replication of the numpy float32 reference.
// ROUND 21: GEMM = R18's verified model (ONE late flip away):
//   SKYLAKEX OpenBLAS, Q=320 halving panels [320,320,320,320,320,224,224],
//   microkernel = TWO k-interleaved accumulator sets (even/odd k),
//   panel close: tot += (p0 + p1)  [combine-then-single-add; R20's
//   sequential variant gave an EARLY flip -> rejected].
// POPNORM fix (this round): multiply form — inv = 1/np.sqrt(var+EPS); e=d*inv
// (literal jax.lax.rsqrt translation). R18 carried R16's division form;
// div-vs-mul differs by 1 ulp on ~30% of elements -> lambda ~= 1 late flip:
// exactly R18's residual (0.0132 = 0.2*|Wm| single late layer-2 flip).
// R16's "null" was misread: with the then-wrong GEMM, the dominant early
// flip-row masked the lambda~1 div/mul difference.
// - mean/var: numpy pairwise_sum (128-leaf, 8 accs, balanced tree) [verified]
// - LIF: f32 transcription order [verified exact]
// Workspace: ~117.5 MB. Dims: T=5, B=4096, D=U=K=2048, O=1024.

// ---------------------------------------------------------------------------
// sgemm replica: C[M,N] = A[M,K] @ B[K,N] (+ bias), all f32.
// 64x64 tile, 256 threads, 4x4 outputs/thread, BK=32 chunks, k ascending.
// TWO accumulator sets: even kk -> pan0, odd kk -> pan1.
// Panel close: tot += (pan0 + pan1).
// ---------------------------------------------------------------------------
__global__ __launch_bounds__(256) void sgemm_np(
    const float* __restrict__ A, const float* __restrict__ B,
    float* __restrict__ C, int N, int K,
    unsigned long long closemask, const float* __restrict__ bias)
{
#pragma clang fp contract(off)
    __shared__ float As[64][32];
    __shared__ float Bs[32][65];

    const int tid  = threadIdx.x;
    const int row0 = blockIdx.x * 64;
    const int col0 = blockIdx.y * 64;
    const int tx = tid & 15, ty = tid >> 4;

    float tot[4][4]  = {};
    float pan0[4][4] = {};
    float pan1[4][4] = {};

    const int nkc = K >> 5;
    for (int kc = 0; kc < nkc; ++kc) {
        const int k0 = kc << 5;
#pragma unroll
        for (int i = 0; i < 8; ++i) {                // stage A: 64x32
            const int idx = tid + 256 * i;
            const int r = idx >> 5, kk = idx & 31;
            As[r][kk] = A[(size_t)(row0 + r) * K + (k0 + kk)];
        }
#pragma unroll
        for (int i = 0; i < 8; ++i) {                // stage B: 32x64
            const int idx = tid + 256 * i;
            const int kk = idx >> 6, c = idx & 63;
            Bs[kk][c] = B[(size_t)(k0 + kk) * N + (col0 + c)];
        }
        __syncthreads();

#pragma unroll
        for (int kk = 0; kk < 32; kk += 2) {         // k ascending, 2-acc
            float a0[4], b0[4], a1[4], b1[4];
#pragma unroll
            for (int j = 0; j < 4; ++j) {
                a0[j] = As[ty * 4 + j][kk];
                a1[j] = As[ty * 4 + j][kk + 1];
                b0[j] = Bs[kk][tx * 4 + j];
                b1[j] = Bs[kk + 1][tx * 4 + j];
            }
#pragma unroll
            for (int x = 0; x < 4; ++x)
#pragma unroll
                for (int y = 0; y < 4; ++y) {
                    pan0[x][y] = __builtin_fmaf(a0[x], b0[y], pan0[x][y]);
                    pan1[x][y] = __builtin_fmaf(a1[x], b1[y], pan1[x][y]);
                }
        }
        if ((closemask >> kc) & 1ull) {              // panel boundary
#pragma unroll
            for (int x = 0; x < 4; ++x)
#pragma unroll
                for (int y = 0; y < 4; ++y) {
                    tot[x][y] = tot[x][y] + (pan0[x][y] + pan1[x][y]);
                    pan0[x][y] = 0.0f;
                    pan1[x][y] = 0.0f;
                }
        }
        __syncthreads();
    }

#pragma unroll
    for (int x = 0; x < 4; ++x) {
        const int r = row0 + ty * 4 + x;
#pragma unroll
        for (int y = 0; y < 4; ++y) {
            const int c = col0 + tx * 4 + y;
            float v = tot[x][y];
            if (bias) v = v + bias[c];
            C[(size_t)r * N + c] = v;
        }
    }
}

// ---------------------------------------------------------------------------
// numpy pairwise_sum. 128-elem leaf: 8 accumulators, combine
// ((r0+r1)+(r2+r3)) + ((r4+r5)+(r6+r7)); 2048 = balanced binary tree over
// 16 consecutive 128-leaves. Order identical for scalar and SIMD builds.
// ---------------------------------------------------------------------------
__device__ __forceinline__ float np_leaf128(const float* a) {
#pragma clang fp contract(off)
    float r0 = a[0], r1 = a[1], r2 = a[2], r3 = a[3];
    float r4 = a[4], r5 = a[5], r6 = a[6], r7 = a[7];
    for (int i = 8; i < 128; i += 8) {
        r0 += a[i + 0]; r1 += a[i + 1]; r2 += a[i + 2]; r3 += a[i + 3];
        r4 += a[i + 4]; r5 += a[i + 5]; r6 += a[i + 6]; r7 += a[i + 7];
    }
    return ((r0 + r1) + (r2 + r3)) + ((r4 + r5) + (r6 + r7));
}

__device__ __forceinline__ float np_tree16(const float* leaf) {
#pragma clang fp contract(off)
    float s256[8], s512[4], s1024[2];
    for (int t = 0; t < 8; ++t) s256[t]  = leaf[2 * t] + leaf[2 * t + 1];
    for (int t = 0; t < 4; ++t) s512[t]  = s256[2 * t] + s256[2 * t + 1];
    for (int t = 0; t < 2; ++t) s1024[t] = s512[2 * t] + s512[2 * t + 1];
    return s1024[0] + s1024[1];
}

// ---------------------------------------------------------------------------
// popnorm + LIF, f32, numpy op order. One block per row (2048 features).
// MULTIPLY form: inv = 1/sqrt(var+eps); e = d*inv  [this round's change]
// ---------------------------------------------------------------------------
__global__ __launch_bounds__(256) void norm_lif_np(
    const float* __restrict__ Y, const float* __restrict__ g,
    const float* __restrict__ b, float* __restrict__ mem,
    float* __restrict__ S, float* __restrict__ Sacc)
{
#pragma clang fp contract(off)
    __shared__ float ly[2048];
    __shared__ float lsq[2048];
    __shared__ float leaf[16];
    __shared__ float stat[2];

    const size_t base = (size_t)blockIdx.x * 2048;
    const int tid = threadIdx.x;

#pragma unroll
    for (int i = 0; i < 8; ++i)
        ly[tid + 256 * i] = Y[base + tid + 256 * i];
    __syncthreads();

    if (tid < 16) leaf[tid] = np_leaf128(&ly[tid * 128]);
    __syncthreads();
    if (tid == 0) stat[0] = np_tree16(leaf) / 2048.0f;   // mu (np.mean)
    __syncthreads();
    const float mu = stat[0];

#pragma unroll
    for (int i = 0; i < 8; ++i) {
        const int j = tid + 256 * i;
        const float d = ly[j] - mu;                      // np.var: (x - mean)
        lsq[j] = d * d;                                  // squared
    }
    __syncthreads();
    if (tid < 16) leaf[tid] = np_leaf128(&lsq[tid * 128]);
    __syncthreads();
    if (tid == 0) {
        const float var = np_tree16(leaf) / 2048.0f;
        stat[1] = 1.0f / sqrtf(var + 1e-5f);             // 1/np.sqrt(var+EPS)
    }
    __syncthreads();
    const float inv = stat[1];

#pragma unroll
    for (int i = 0; i < 8; ++i) {
        const int j = tid + 256 * i;
        const float d  = ly[j] - mu;     // (x - mu)
        const float e  = d * inv;        // * rsqrt  [MULTIPLY form]
        const float f  = e * g[j];       // * g   (exact: g == 1)
        const float h1 = f + b[j];       // + b   (exact: b == 0)
        const float h  = 0.5f * h1;      // THR *
        const float m  = mem[base + j];
        const float t1 = h - m;          // (x - mem)
        const float t2 = t1 / 2.0f;      // / TAU (exact)
        const float mn = m + t2;         // mem +
        const float sp = ((mn - 0.5f) > 0.0f) ? 1.0f : 0.0f;  // heaviside
        mem[base + j] = mn * (1.0f - sp);                     // hard reset
        if (S)    S[base + j] = sp;
        if (Sacc) Sacc[base + j] = Sacc[base + j] + sp;       // exact int add
    }
}

// outs = counts / 5.0f  (np.mean over T: exact int sum, then f32 divide)
__global__ __launch_bounds__(256) void div5(float* __restrict__ p) {
#pragma clang fp contract(off)
    const int i = blockIdx.x * 256 + threadIdx.x;
    p[i] = p[i] / 5.0f;
}

// ---------------------------------------------------------------------------
extern "C" void kernel_launch(void* const* d_in, const int* in_sizes, int n_in,
                              void* d_out, int out_size, void* d_ws, size_t ws_size,
                              hipStream_t stream)
{
    const float* features = (const float*)d_in[0];
    const float* W0 = (const float*)d_in[1];
    const float* g0 = (const float*)d_in[2];
    const float* b0 = (const float*)d_in[3];
    const float* W1 = (const float*)d_in[4];
    const float* g1 = (const float*)d_in[5];
    const float* b1 = (const float*)d_in[6];
    const float* W2 = (const float*)d_in[7];
    const float* g2 = (const float*)d_in[8];
    const float* b2 = (const float*)d_in[9];
    const float* Wm = (const float*)d_in[10];
    const float* bm = (const float*)d_in[11];
    float* out = (float*)d_out;

    const size_t SB  = 4096ull * 2048ull;   // full-batch elems
    const size_t CHE = 2048ull * 2048ull;   // chunk elems (2048 rows)

    float* y    = (float*)d_ws;     // 16.8 MB
    float* m0   = y  + CHE;         // 50.3 MB (m0,m1,m2 contiguous)
    float* m1   = m0 + CHE;
    float* m2   = m1 + CHE;
    float* S    = m2 + CHE;         // 16.8 MB
    float* Sacc = S  + CHE;         // 33.6 MB (full batch)
    // total ~117.5 MB

    // SKYLAKEX Q=320 + halving: panels [320x5, 224, 224]
    // ends at chunks {10,20,30,40,50,57,64}-1 -> bits {9,19,29,39,49,56,63}
    const unsigned long long cm =
        (1ull << 9)  | (1ull << 19) | (1ull << 29) |
        (1ull << 39) | (1ull << 49) | (1ull << 56) | (1ull << 63);

    hipMemsetAsync(Sacc, 0, SB * 4, stream);

    for (int c = 0; c < 2; ++c) {
        const size_t r0 = (size_t)c * 2048;
        hipMemsetAsync(m0, 0, CHE * 4 * 3, stream);   // zero m0,m1,m2

        for (int t = 0; t < 5; ++t) {
            const float* xt = features + (size_t)t * SB + r0 * 2048;
            sgemm_np<<<dim3(32, 32), 256, 0, stream>>>(
                xt, W0, y, 2048, 2048, cm, nullptr);
            norm_lif_np<<<2048, 256, 0, stream>>>(y, g0, b0, m0, S, nullptr);

            sgemm_np<<<dim3(32, 32), 256, 0, stream>>>(
                S, W1, y, 2048, 2048, cm, nullptr);
            norm_lif_np<<<2048, 256, 0, stream>>>(y, g1, b1, m1, S, nullptr);

            sgemm_np<<<dim3(32, 32), 256, 0, stream>>>(
                S, W2, y, 2048, 2048, cm, nullptr);
            norm_lif_np<<<2048, 256, 0, stream>>>(y, g2, b2, m2, nullptr,
                                                  Sacc + r0 * 2048);
        }
    }

    // outs = Sacc / 5 (in place), then head: out = outs @ Wm + bm
    div5<<<SB / 256, 256, 0, stream>>>(Sacc);
    sgemm_np<<<dim3(64, 16), 256, 0, stream>>>(
        Sacc, Wm, out, 1024, 2048, cm, bm);
}

// Round 22
// 11005.552 us; speedup vs baseline: 1.1034x; 1.1034x over previous
//
#include <hip/hip_runtime.h>

// SpikeMLP: bit-exact replica of the np reference (PASSED R21), optimized.
// FROZEN association (verified): SKX OpenBLAS sgemm — Q=320 halving panels
// [320,320,320,320,320,224,224]; per element TWO k-interleaved FMA chains
// (even/odd k, ascending); panel close: tot += (p0+p1); + numpy pairwise
// mean/var (128-leaf/8-acc); multiply-form popnorm; f32 LIF transcription.
// R22 optimization (association-neutral): k-major LDS + ds_read_b128 frags,
// 8x4 register tile (128x64 block), double-buffered LDS w/ register-staged
// globals + ONE barrier/chunk, conflict-free staging, merged batch chunks.
// Workspace: ~201 MB. Dims: T=5, B=4096, D=U=K=2048, O=1024.

#define WA 132   // Ak row stride (f32), 16B-aligned, conflict-free reads
#define WB 68    // Bk row stride

// ---------------------------------------------------------------------------
// sgemm replica: C[M,N] = A[M,K] @ B[K,N] (+ bias), all f32.
// 128x64 tile, 256 threads, 8x4 outputs/thread, BK=32 chunks, k ascending.
// Two accumulator chains (even/odd k); closemask bit kc => panel close.
// LDS k-major double-buffered; global loads register-staged one chunk ahead.
// ---------------------------------------------------------------------------
__global__ __launch_bounds__(256) void sgemm_np(
    const float* __restrict__ A, const float* __restrict__ B,
    float* __restrict__ C, int N, int K,
    unsigned long long closemask, const float* __restrict__ bias)
{
#pragma clang fp contract(off)
    __shared__ float Ak[2][32][WA];   // [buf][kk][r], r < 128
    __shared__ float Bk[2][32][WB];   // [buf][kk][c], c < 64

    const int tid  = threadIdx.x;
    const int row0 = blockIdx.x * 128;
    const int col0 = blockIdx.y * 64;
    const int rg = tid >> 4;          // 0..15: rows rg*8..+7
    const int cg = tid & 15;          // 0..15: cols cg*4..+3

    // staging thread mapping
    const int sq = tid & 7;           // A k-quad (sq*4..+3)
    const int sr = tid >> 3;          // A row base (0..31, 4 sweeps of 32)
    const int bc = tid & 15;          // B col quad
    const int bk = tid >> 4;          // B k (0..15, 2 sweeps of 16)

    float tot[8][4] = {};
    float p0[8][4]  = {};
    float p1[8][4]  = {};

    float4 sa[4], sb[2];

    auto gload = [&](int kc) {
        const int k0 = kc << 5;
#pragma unroll
        for (int i = 0; i < 4; ++i)
            sa[i] = *(const float4*)&A[(size_t)(row0 + sr + 32 * i) * K + k0 + sq * 4];
#pragma unroll
        for (int i = 0; i < 2; ++i)
            sb[i] = *(const float4*)&B[(size_t)(k0 + bk + 16 * i) * N + col0 + bc * 4];
    };
    auto lwrite = [&](int buf) {
#pragma unroll
        for (int i = 0; i < 4; ++i) {
            const float v[4] = {sa[i].x, sa[i].y, sa[i].z, sa[i].w};
#pragma unroll
            for (int j = 0; j < 4; ++j) {
                const int jj = (j + sq) & 3;          // bank-derotated order
                Ak[buf][sq * 4 + jj][sr + 32 * i] = v[jj];
            }
        }
#pragma unroll
        for (int i = 0; i < 2; ++i)
            *(float4*)&Bk[buf][bk + 16 * i][bc * 4] = sb[i];
    };

    const int nkc = K >> 5;
    gload(0);
    lwrite(0);
    __syncthreads();

    for (int kc = 0; kc < nkc; ++kc) {
        const int buf = kc & 1;
        if (kc + 1 < nkc) gload(kc + 1);   // latency hides under compute

        const float* ab = &Ak[buf][0][rg * 8];
        const float* bb = &Bk[buf][0][cg * 4];
#pragma unroll
        for (int kk = 0; kk < 32; kk += 2) {   // k ascending, 2 chains
            const float4 al0 = *(const float4*)(ab + kk * WA);
            const float4 ah0 = *(const float4*)(ab + kk * WA + 4);
            const float4 al1 = *(const float4*)(ab + (kk + 1) * WA);
            const float4 ah1 = *(const float4*)(ab + (kk + 1) * WA + 4);
            const float4 bv0 = *(const float4*)(bb + kk * WB);
            const float4 bv1 = *(const float4*)(bb + (kk + 1) * WB);
            const float a0[8] = {al0.x, al0.y, al0.z, al0.w,
                                 ah0.x, ah0.y, ah0.z, ah0.w};
            const float a1[8] = {al1.x, al1.y, al1.z, al1.w,
                                 ah1.x, ah1.y, ah1.z, ah1.w};
            const float c0[4] = {bv0.x, bv0.y, bv0.z, bv0.w};
            const float c1[4] = {bv1.x, bv1.y, bv1.z, bv1.w};
#pragma unroll
            for (int x = 0; x < 8; ++x)
#pragma unroll
                for (int y = 0; y < 4; ++y) {
                    p0[x][y] = __builtin_fmaf(a0[x], c0[y], p0[x][y]);
                    p1[x][y] = __builtin_fmaf(a1[x], c1[y], p1[x][y]);
                }
        }
        if ((closemask >> kc) & 1ull) {        // panel boundary (uniform)
#pragma unroll
            for (int x = 0; x < 8; ++x)
#pragma unroll
                for (int y = 0; y < 4; ++y) {
                    tot[x][y] = tot[x][y] + (p0[x][y] + p1[x][y]);
                    p0[x][y] = 0.0f;
                    p1[x][y] = 0.0f;
                }
        }
        // one barrier per chunk: reads of buf done block-wide before next
        // iter reads buf^1 (written below); write target buf^1 was last
        // READ two iters ago, separated by the previous barrier.
        if (kc + 1 < nkc) {
            __syncthreads();
            lwrite(buf ^ 1);
            __syncthreads();
        }
    }

#pragma unroll
    for (int x = 0; x < 8; ++x) {
        const int r = row0 + rg * 8 + x;
        const int c = col0 + cg * 4;
        float4 v;
        v.x = tot[x][0]; v.y = tot[x][1]; v.z = tot[x][2]; v.w = tot[x][3];
        if (bias) {
            v.x = v.x + bias[c + 0];
            v.y = v.y + bias[c + 1];
            v.z = v.z + bias[c + 2];
            v.w = v.w + bias[c + 3];
        }
        *(float4*)&C[(size_t)r * N + c] = v;
    }
}

// ---------------------------------------------------------------------------
// numpy pairwise_sum. 128-elem leaf: 8 accumulators, combine
// ((r0+r1)+(r2+r3)) + ((r4+r5)+(r6+r7)); 2048 = balanced binary tree over
// 16 consecutive 128-leaves. [verified exact]
// ---------------------------------------------------------------------------
__device__ __forceinline__ float np_leaf128(const float* a) {
#pragma clang fp contract(off)
    float r0 = a[0], r1 = a[1], r2 = a[2], r3 = a[3];
    float r4 = a[4], r5 = a[5], r6 = a[6], r7 = a[7];
    for (int i = 8; i < 128; i += 8) {
        r0 += a[i + 0]; r1 += a[i + 1]; r2 += a[i + 2]; r3 += a[i + 3];
        r4 += a[i + 4]; r5 += a[i + 5]; r6 += a[i + 6]; r7 += a[i + 7];
    }
    return ((r0 + r1) + (r2 + r3)) + ((r4 + r5) + (r6 + r7));
}

__device__ __forceinline__ float np_tree16(const float* leaf) {
#pragma clang fp contract(off)
    float s256[8], s512[4], s1024[2];
    for (int t = 0; t < 8; ++t) s256[t]  = leaf[2 * t] + leaf[2 * t + 1];
    for (int t = 0; t < 4; ++t) s512[t]  = s256[2 * t] + s256[2 * t + 1];
    for (int t = 0; t < 2; ++t) s1024[t] = s512[2 * t] + s512[2 * t + 1];
    return s1024[0] + s1024[1];
}

// ---------------------------------------------------------------------------
// popnorm + LIF, f32, numpy op order. One block per row (2048 features).
// Multiply form: inv = 1/sqrt(var+eps); e = d*inv. [verified exact]
// ---------------------------------------------------------------------------
__global__ __launch_bounds__(256) void norm_lif_np(
    const float* __restrict__ Y, const float* __restrict__ g,
    const float* __restrict__ b, float* __restrict__ mem,
    float* __restrict__ S, float* __restrict__ Sacc)
{
#pragma clang fp contract(off)
    __shared__ float ly[2048];
    __shared__ float lsq[2048];
    __shared__ float leaf[16];
    __shared__ float stat[2];

    const size_t base = (size_t)blockIdx.x * 2048;
    const int tid = threadIdx.x;

#pragma unroll
    for (int i = 0; i < 8; ++i)
        ly[tid + 256 * i] = Y[base + tid + 256 * i];
    __syncthreads();

    if (tid < 16) leaf[tid] = np_leaf128(&ly[tid * 128]);
    __syncthreads();
    if (tid == 0) stat[0] = np_tree16(leaf) / 2048.0f;   // mu (np.mean)
    __syncthreads();
    const float mu = stat[0];

#pragma unroll
    for (int i = 0; i < 8; ++i) {
        const int j = tid + 256 * i;
        const float d = ly[j] - mu;                      // np.var
        lsq[j] = d * d;
    }
    __syncthreads();
    if (tid < 16) leaf[tid] = np_leaf128(&lsq[tid * 128]);
    __syncthreads();
    if (tid == 0) {
        const float var = np_tree16(leaf) / 2048.0f;
        stat[1] = 1.0f / sqrtf(var + 1e-5f);             // 1/np.sqrt(var+EPS)
    }
    __syncthreads();
    const float inv = stat[1];

#pragma unroll
    for (int i = 0; i < 8; ++i) {
        const int j = tid + 256 * i;
        const float d  = ly[j] - mu;     // (x - mu)
        const float e  = d * inv;        // * rsqrt  [multiply form]
        const float f  = e * g[j];       // * g   (exact: g == 1)
        const float h1 = f + b[j];       // + b   (exact: b == 0)
        const float h  = 0.5f * h1;      // THR *
        const float m  = mem[base + j];
        const float t1 = h - m;          // (x - mem)
        const float t2 = t1 / 2.0f;      // / TAU (exact)
        const float mn = m + t2;         // mem +
        const float sp = ((mn - 0.5f) > 0.0f) ? 1.0f : 0.0f;  // heaviside
        mem[base + j] = mn * (1.0f - sp);                     // hard reset
        if (S)    S[base + j] = sp;
        if (Sacc) Sacc[base + j] = Sacc[base + j] + sp;       // exact int add
    }
}

// outs = counts / 5.0f  (np.mean over T: exact int sum, then f32 divide)
__global__ __launch_bounds__(256) void div5(float* __restrict__ p) {
#pragma clang fp contract(off)
    const int i = blockIdx.x * 256 + threadIdx.x;
    p[i] = p[i] / 5.0f;
}

// ---------------------------------------------------------------------------
extern "C" void kernel_launch(void* const* d_in, const int* in_sizes, int n_in,
                              void* d_out, int out_size, void* d_ws, size_t ws_size,
                              hipStream_t stream)
{
    const float* features = (const float*)d_in[0];
    const float* W0 = (const float*)d_in[1];
    const float* g0 = (const float*)d_in[2];
    const float* b0 = (const float*)d_in[3];
    const float* W1 = (const float*)d_in[4];
    const float* g1 = (const float*)d_in[5];
    const float* b1 = (const float*)d_in[6];
    const float* W2 = (const float*)d_in[7];
    const float* g2 = (const float*)d_in[8];
    const float* b2 = (const float*)d_in[9];
    const float* Wm = (const float*)d_in[10];
    const float* bm = (const float*)d_in[11];
    float* out = (float*)d_out;

    const size_t SB = 4096ull * 2048ull;   // full-batch elems

    float* y    = (float*)d_ws;     // 33.6 MB
    float* m0   = y  + SB;          // m0,m1,m2 contiguous (100.7 MB)
    float* m1   = m0 + SB;
    float* m2   = m1 + SB;
    float* S    = m2 + SB;          // 33.6 MB
    float* Sacc = S  + SB;          // 33.6 MB
    // total ~201 MB

    // SKYLAKEX Q=320 + halving: panels [320x5, 224, 224]
    // ends at chunks {10,20,30,40,50,57,64}-1 -> bits {9,19,29,39,49,56,63}
    const unsigned long long cm =
        (1ull << 9)  | (1ull << 19) | (1ull << 29) |
        (1ull << 39) | (1ull << 49) | (1ull << 56) | (1ull << 63);

    hipMemsetAsync(m0, 0, SB * 4 * 3, stream);   // m0,m1,m2
    hipMemsetAsync(Sacc, 0, SB * 4, stream);

    for (int t = 0; t < 5; ++t) {
        const float* xt = features + (size_t)t * SB;
        sgemm_np<<<dim3(32, 32), 256, 0, stream>>>(
            xt, W0, y, 2048, 2048, cm, nullptr);
        norm_lif_np<<<4096, 256, 0, stream>>>(y, g0, b0, m0, S, nullptr);

        sgemm_np<<<dim3(32, 32), 256, 0, stream>>>(
            S, W1, y, 2048, 2048, cm, nullptr);
        norm_lif_np<<<4096, 256, 0, stream>>>(y, g1, b1, m1, S, nullptr);

        sgemm_np<<<dim3(32, 32), 256, 0, stream>>>(
            S, W2, y, 2048, 2048, cm, nullptr);
        norm_lif_np<<<4096, 256, 0, stream>>>(y, g2, b2, m2, nullptr, Sacc);
    }

    // outs = Sacc / 5 (in place), then head: out = outs @ Wm + bm
    div5<<<SB / 256, 256, 0, stream>>>(Sacc);
    sgemm_np<<<dim3(32, 16), 256, 0, stream>>>(
        Sacc, Wm, out, 1024, 2048, cm, bm);
}